// Round 3
// baseline (504.506 us; speedup 1.0000x reference)
//
#include <hip/hip_runtime.h>

// AFGCN: N=50000 nodes, E=600000 edges, D=128, L=4.
// Inputs: x[N,128] f32, edge_index[2,E] int, Wn[4,128,128] f32, Wr[4,128,128] f32,
//         b[4,128] f32, fcW[128,1] f32, fcb[1] f32. Output: [N] f32.

#define D 128

__global__ void k_zero_i32(int* __restrict__ p, int n) {
    int i = blockIdx.x * blockDim.x + threadIdx.x;
    if (i < n) p[i] = 0;
}

__global__ void k_hist(const int* __restrict__ dst, int* __restrict__ cnt, int e) {
    int i = blockIdx.x * blockDim.x + threadIdx.x;
    if (i < e) atomicAdd(&cnt[dst[i]], 1);
}

// phase A: per-block exclusive scan of 1024 elements (256 thr x 4), block sums out
__global__ __launch_bounds__(256) void k_scan_a(const int* __restrict__ cnt,
                                                int* __restrict__ ro,
                                                int* __restrict__ bsum, int n) {
    __shared__ int s[256];
    int tid = threadIdx.x;
    int base = blockIdx.x * 1024 + tid * 4;
    int c[4];
    #pragma unroll
    for (int k = 0; k < 4; ++k) c[k] = (base + k < n) ? cnt[base + k] : 0;
    int tsum = c[0] + c[1] + c[2] + c[3];
    s[tid] = tsum;
    __syncthreads();
    #pragma unroll
    for (int off = 1; off < 256; off <<= 1) {
        int add = (tid >= off) ? s[tid - off] : 0;
        __syncthreads();
        s[tid] += add;
        __syncthreads();
    }
    int run = (tid == 0) ? 0 : s[tid - 1];
    #pragma unroll
    for (int k = 0; k < 4; ++k) {
        if (base + k < n) ro[base + k] = run;
        run += c[k];
    }
    if (tid == 255) bsum[blockIdx.x] = s[255];
}

// phase B: one wave scans the <=64 block sums (exclusive, in place), writes total
__global__ __launch_bounds__(64) void k_scan_b(int* __restrict__ bsum,
                                               int* __restrict__ ro, int nb, int n) {
    int tid = threadIdx.x;
    int orig = (tid < nb) ? bsum[tid] : 0;
    int v = orig;
    #pragma unroll
    for (int off = 1; off < 64; off <<= 1) {
        int u = __shfl_up(v, off, 64);
        if (tid >= off) v += u;
    }
    if (tid < nb) bsum[tid] = v - orig;    // exclusive block offset
    if (tid == 63) ro[n] = v;              // grand total = E
}

// phase C: add block offsets; write both ro and cur
__global__ __launch_bounds__(256) void k_scan_c(int* __restrict__ ro,
                                                int* __restrict__ cur,
                                                const int* __restrict__ bsum, int n) {
    int base = blockIdx.x * 1024 + threadIdx.x * 4;
    int off = bsum[blockIdx.x];
    #pragma unroll
    for (int k = 0; k < 4; ++k) {
        int i = base + k;
        if (i < n) {
            int v = ro[i] + off;
            ro[i] = v;
            cur[i] = v;
        }
    }
}

__global__ void k_scatter(const int* __restrict__ src, const int* __restrict__ dst,
                          int* __restrict__ cur, int* __restrict__ ssrc, int e) {
    int i = blockIdx.x * blockDim.x + threadIdx.x;
    if (i < e) {
        int pos = atomicAdd(&cur[dst[i]], 1);
        ssrc[pos] = src[i];
    }
}

// 8 nodes per 256-thread block; 32 lanes x float4 cover one 512B row
__global__ __launch_bounds__(256) void k_agg(const float* __restrict__ h,
                                             const int* __restrict__ ro,
                                             const int* __restrict__ ssrc,
                                             float* __restrict__ agg, int n) {
    int node = blockIdx.x * 8 + (threadIdx.x >> 5);
    if (node >= n) return;
    int c4 = (threadIdx.x & 31) << 2;
    int s = ro[node], e = ro[node + 1];
    float4 acc = make_float4(0.f, 0.f, 0.f, 0.f);
    int j = s;
    for (; j + 3 < e; j += 4) {
        const float4 v0 = *(const float4*)&h[(size_t)ssrc[j] * D + c4];
        const float4 v1 = *(const float4*)&h[(size_t)ssrc[j + 1] * D + c4];
        const float4 v2 = *(const float4*)&h[(size_t)ssrc[j + 2] * D + c4];
        const float4 v3 = *(const float4*)&h[(size_t)ssrc[j + 3] * D + c4];
        acc.x += (v0.x + v1.x) + (v2.x + v3.x);
        acc.y += (v0.y + v1.y) + (v2.y + v3.y);
        acc.z += (v0.z + v1.z) + (v2.z + v3.z);
        acc.w += (v0.w + v1.w) + (v2.w + v3.w);
    }
    for (; j < e; ++j) {
        const float4 v = *(const float4*)&h[(size_t)ssrc[j] * D + c4];
        acc.x += v.x; acc.y += v.y; acc.z += v.z; acc.w += v.w;
    }
    *(float4*)&agg[(size_t)node * D + c4] = acc;
}

// h_out = relu(agg @ Wn + hin @ Wr + b) + x0  (LAST: out = h_out @ fcW + fcb)
// 32-row tile, 256 threads: cx=(tid&31)*4 cols, rg=(tid>>5)*4 rows, acc[4][4]
template<bool LAST>
__global__ __launch_bounds__(256) void k_layer(const float* __restrict__ hin,
                                               const float* __restrict__ agg,
                                               const float* __restrict__ Wn,
                                               const float* __restrict__ Wr,
                                               const float* __restrict__ bias,
                                               const float* __restrict__ x0,
                                               float* __restrict__ hout,
                                               const float* __restrict__ fcW,
                                               const float* __restrict__ fcb,
                                               float* __restrict__ out, int n) {
    __shared__ float sa[32][D];
    __shared__ float sh[32][D];
    int tid = threadIdx.x;
    int row0 = blockIdx.x * 32;

    // stage 32x128 agg + h tiles (float4, coalesced, conflict-free)
    for (int i = tid; i < 32 * (D / 4); i += 256) {
        int r = i >> 5;
        int c4 = (i & 31) << 2;
        int gr = row0 + r;
        float4 va = make_float4(0.f, 0.f, 0.f, 0.f), vh = va;
        if (gr < n) {
            va = *(const float4*)&agg[(size_t)gr * D + c4];
            vh = *(const float4*)&hin[(size_t)gr * D + c4];
        }
        *(float4*)&sa[r][c4] = va;
        *(float4*)&sh[r][c4] = vh;
    }
    __syncthreads();

    const int cx = (tid & 31) << 2;   // 4 consecutive cols
    const int rg = (tid >> 5) << 2;   // 4 consecutive rows
    float acc[4][4] = {};

    for (int k0 = 0; k0 < D; k0 += 4) {
        float wn[4][4], wr_[4][4];
        #pragma unroll
        for (int kk = 0; kk < 4; ++kk) {
            float4 t = *(const float4*)&Wn[(k0 + kk) * D + cx];
            wn[kk][0] = t.x; wn[kk][1] = t.y; wn[kk][2] = t.z; wn[kk][3] = t.w;
            float4 u = *(const float4*)&Wr[(k0 + kk) * D + cx];
            wr_[kk][0] = u.x; wr_[kk][1] = u.y; wr_[kk][2] = u.z; wr_[kk][3] = u.w;
        }
        #pragma unroll
        for (int r = 0; r < 4; ++r) {
            // uniform address within 32-lane group -> broadcast, conflict-free
            float4 a4 = *(const float4*)&sa[rg + r][k0];
            float4 h4 = *(const float4*)&sh[rg + r][k0];
            float av[4] = {a4.x, a4.y, a4.z, a4.w};
            float hv[4] = {h4.x, h4.y, h4.z, h4.w};
            #pragma unroll
            for (int kk = 0; kk < 4; ++kk) {
                #pragma unroll
                for (int c = 0; c < 4; ++c) {
                    acc[r][c] = fmaf(av[kk], wn[kk][c],
                               fmaf(hv[kk], wr_[kk][c], acc[r][c]));
                }
            }
        }
    }

    float bb[4];
    {
        float4 t = *(const float4*)&bias[cx];
        bb[0] = t.x; bb[1] = t.y; bb[2] = t.z; bb[3] = t.w;
    }

    if (!LAST) {
        #pragma unroll
        for (int r = 0; r < 4; ++r) {
            int gr = row0 + rg + r;
            if (gr >= n) break;
            float4 xr = *(const float4*)&x0[(size_t)gr * D + cx];
            float4 o;
            o.x = fmaxf(acc[r][0] + bb[0], 0.f) + xr.x;
            o.y = fmaxf(acc[r][1] + bb[1], 0.f) + xr.y;
            o.z = fmaxf(acc[r][2] + bb[2], 0.f) + xr.z;
            o.w = fmaxf(acc[r][3] + bb[3], 0.f) + xr.w;
            *(float4*)&hout[(size_t)gr * D + cx] = o;
        }
    } else {
        float fw[4];
        float4 t = *(const float4*)&fcW[cx];
        fw[0] = t.x; fw[1] = t.y; fw[2] = t.z; fw[3] = t.w;
        float fb = fcb[0];
        #pragma unroll
        for (int r = 0; r < 4; ++r) {
            int gr = row0 + rg + r;
            float p = 0.f;
            if (gr < n) {
                float4 xr = *(const float4*)&x0[(size_t)gr * D + cx];
                p += (fmaxf(acc[r][0] + bb[0], 0.f) + xr.x) * fw[0];
                p += (fmaxf(acc[r][1] + bb[1], 0.f) + xr.y) * fw[1];
                p += (fmaxf(acc[r][2] + bb[2], 0.f) + xr.z) * fw[2];
                p += (fmaxf(acc[r][3] + bb[3], 0.f) + xr.w) * fw[3];
            }
            #pragma unroll
            for (int off = 16; off > 0; off >>= 1)
                p += __shfl_down(p, off, 32);   // width 32: stays in col-group
            if ((tid & 31) == 0 && gr < n) out[gr] = p + fb;
        }
    }
}

extern "C" void kernel_launch(void* const* d_in, const int* in_sizes, int n_in,
                              void* d_out, int out_size, void* d_ws, size_t ws_size,
                              hipStream_t stream) {
    const float* x    = (const float*)d_in[0];
    const int*   ei   = (const int*)d_in[1];
    const float* Wn   = (const float*)d_in[2];
    const float* Wr   = (const float*)d_in[3];
    const float* bias = (const float*)d_in[4];
    const float* fcW  = (const float*)d_in[5];
    const float* fcb  = (const float*)d_in[6];
    float* out = (float*)d_out;

    const int n = in_sizes[0] / D;     // 50000
    const int e = in_sizes[1] / 2;     // 600000

    const int* src = ei;
    const int* dst = ei + e;

    // workspace layout
    char* ws = (char*)d_ws;
    float* h_a   = (float*)ws;                         ws += (size_t)n * D * 4;
    float* h_b   = (float*)ws;                         ws += (size_t)n * D * 4;
    float* agg   = (float*)ws;                         ws += (size_t)n * D * 4;
    int*   ro    = (int*)ws;                           ws += (size_t)(n + 1) * 4;
    int*   cur   = (int*)ws;                           ws += (size_t)n * 4;
    int*   ssrc  = (int*)ws;                           ws += (size_t)e * 4;
    int*   bsum  = (int*)ws;                           ws += 256 * 4;
    (void)ws_size;

    const int nscan = (n + 1023) / 1024;   // 49 blocks

    // ---- CSR build
    k_zero_i32<<<(n + 255) / 256, 256, 0, stream>>>(cur, n);
    k_hist<<<(e + 255) / 256, 256, 0, stream>>>(dst, cur, e);
    k_scan_a<<<nscan, 256, 0, stream>>>(cur, ro, bsum, n);
    k_scan_b<<<1, 64, 0, stream>>>(bsum, ro, nscan, n);
    k_scan_c<<<nscan, 256, 0, stream>>>(ro, cur, bsum, n);
    k_scatter<<<(e + 255) / 256, 256, 0, stream>>>(src, dst, cur, ssrc, e);

    // ---- layers
    const int layer_blocks = (n + 31) / 32;
    const int agg_blocks = (n + 7) / 8;

    // layer 0
    k_agg<<<agg_blocks, 256, 0, stream>>>(x, ro, ssrc, agg, n);
    k_layer<false><<<layer_blocks, 256, 0, stream>>>(x, agg, Wn, Wr, bias, x,
            h_a, fcW, fcb, out, n);
    // layer 1
    k_agg<<<agg_blocks, 256, 0, stream>>>(h_a, ro, ssrc, agg, n);
    k_layer<false><<<layer_blocks, 256, 0, stream>>>(h_a, agg,
            Wn + 1 * D * D, Wr + 1 * D * D, bias + 1 * D, x, h_b, fcW, fcb, out, n);
    // layer 2
    k_agg<<<agg_blocks, 256, 0, stream>>>(h_b, ro, ssrc, agg, n);
    k_layer<false><<<layer_blocks, 256, 0, stream>>>(h_b, agg,
            Wn + 2 * D * D, Wr + 2 * D * D, bias + 2 * D, x, h_a, fcW, fcb, out, n);
    // layer 3 (fused final fc)
    k_agg<<<agg_blocks, 256, 0, stream>>>(h_a, ro, ssrc, agg, n);
    k_layer<true><<<layer_blocks, 256, 0, stream>>>(h_a, agg,
            Wn + 3 * D * D, Wr + 3 * D * D, bias + 3 * D, x, h_b, fcW, fcb, out, n);
}

// Round 4
// 273.648 us; speedup vs baseline: 1.8436x; 1.8436x over previous
//
#include <hip/hip_runtime.h>

// AFGCN: N=50000, E=600000, D=128, L=4. bf16 storage + MFMA, f32 accumulate.

#define D 128

using bf16x8 = __attribute__((ext_vector_type(8))) short;
using f32x4  = __attribute__((ext_vector_type(4))) float;

__device__ inline unsigned short f2b(float f) {
    union { float f; unsigned int u; } v; v.f = f;
    unsigned int u = v.u;
    u += 0x7fffu + ((u >> 16) & 1u);   // round-to-nearest-even
    return (unsigned short)(u >> 16);
}
__device__ inline float b2f_lo(unsigned int u) { return __uint_as_float(u << 16); }
__device__ inline float b2f_hi(unsigned int u) { return __uint_as_float(u & 0xffff0000u); }

// ---------------- CSR build ----------------
__global__ void k_zero_i32(int* __restrict__ p, int n) {
    int i = blockIdx.x * blockDim.x + threadIdx.x;
    if (i < n) p[i] = 0;
}

__global__ void k_hist(const int* __restrict__ dst, int* __restrict__ cnt, int e) {
    int i = blockIdx.x * blockDim.x + threadIdx.x;
    if (i < e) atomicAdd(&cnt[dst[i]], 1);
}

__global__ __launch_bounds__(256) void k_scan_a(const int* __restrict__ cnt,
                                                int* __restrict__ ro,
                                                int* __restrict__ bsum, int n) {
    __shared__ int s[256];
    int tid = threadIdx.x;
    int base = blockIdx.x * 1024 + tid * 4;
    int c[4];
    #pragma unroll
    for (int k = 0; k < 4; ++k) c[k] = (base + k < n) ? cnt[base + k] : 0;
    s[tid] = c[0] + c[1] + c[2] + c[3];
    __syncthreads();
    #pragma unroll
    for (int off = 1; off < 256; off <<= 1) {
        int add = (tid >= off) ? s[tid - off] : 0;
        __syncthreads();
        s[tid] += add;
        __syncthreads();
    }
    int run = (tid == 0) ? 0 : s[tid - 1];
    #pragma unroll
    for (int k = 0; k < 4; ++k) {
        if (base + k < n) ro[base + k] = run;
        run += c[k];
    }
    if (tid == 255) bsum[blockIdx.x] = s[255];
}

__global__ __launch_bounds__(64) void k_scan_b(int* __restrict__ bsum,
                                               int* __restrict__ ro, int nb, int n) {
    int tid = threadIdx.x;
    int orig = (tid < nb) ? bsum[tid] : 0;
    int v = orig;
    #pragma unroll
    for (int off = 1; off < 64; off <<= 1) {
        int u = __shfl_up(v, off, 64);
        if (tid >= off) v += u;
    }
    if (tid < nb) bsum[tid] = v - orig;
    if (tid == 63) ro[n] = v;
}

__global__ __launch_bounds__(256) void k_scan_c(int* __restrict__ ro,
                                                int* __restrict__ cur,
                                                const int* __restrict__ bsum, int n) {
    int base = blockIdx.x * 1024 + threadIdx.x * 4;
    int off = bsum[blockIdx.x];
    #pragma unroll
    for (int k = 0; k < 4; ++k) {
        int i = base + k;
        if (i < n) { int v = ro[i] + off; ro[i] = v; cur[i] = v; }
    }
}

__global__ void k_scatter(const int* __restrict__ src, const int* __restrict__ dst,
                          int* __restrict__ cur, int* __restrict__ ssrc, int e) {
    int i = blockIdx.x * blockDim.x + threadIdx.x;
    if (i < e) {
        int pos = atomicAdd(&cur[dst[i]], 1);
        ssrc[pos] = src[i];
    }
}

// ---------------- prep ----------------
// f32 -> bf16, 8 elems per thread
__global__ void k_cvt(const float* __restrict__ in, unsigned short* __restrict__ out,
                      int n8) {
    int i = blockIdx.x * blockDim.x + threadIdx.x;
    if (i >= n8) return;
    float4 a = ((const float4*)in)[i * 2];
    float4 b = ((const float4*)in)[i * 2 + 1];
    ushort4 o0, o1;
    o0.x = f2b(a.x); o0.y = f2b(a.y); o0.z = f2b(a.z); o0.w = f2b(a.w);
    o1.x = f2b(b.x); o1.y = f2b(b.y); o1.z = f2b(b.z); o1.w = f2b(b.w);
    ((ushort4*)out)[i * 2] = o0;
    ((ushort4*)out)[i * 2 + 1] = o1;
}

// Pack Bcat = [Wn;Wr] (256x128) into MFMA fragment order, bf16:
// Bp[layer][ks(8)][nb(8)][lane(64)][8]  where n = nb*16+(lane&15), k = ks*32+(lane>>4)*8+j
__global__ void k_pack_B(const float* __restrict__ Wn, const float* __restrict__ Wr,
                         unsigned short* __restrict__ Bp) {
    int t = blockIdx.x * blockDim.x + threadIdx.x;   // < 4*8*8*64
    int lane = t & 63;
    int nb = (t >> 6) & 7;
    int ks = (t >> 9) & 7;
    int l  = t >> 12;
    int ncol = nb * 16 + (lane & 15);
    int k0 = ks * 32 + (lane >> 4) * 8;
    ushort4 lo, hi;
    unsigned short v[8];
    #pragma unroll
    for (int j = 0; j < 8; ++j) {
        int k = k0 + j;
        float f = (k < D) ? Wn[(size_t)l * D * D + k * D + ncol]
                          : Wr[(size_t)l * D * D + (k - D) * D + ncol];
        v[j] = f2b(f);
    }
    lo.x = v[0]; lo.y = v[1]; lo.z = v[2]; lo.w = v[3];
    hi.x = v[4]; hi.y = v[5]; hi.z = v[6]; hi.w = v[7];
    ((ushort4*)Bp)[t * 2] = lo;
    ((ushort4*)Bp)[t * 2 + 1] = hi;
}

// ---------------- aggregation (bf16 in/out, f32 accum) ----------------
// 16 nodes per 256-thread block; 16 lanes x 16B cover one 256B row
__global__ __launch_bounds__(256) void k_agg_b(const unsigned short* __restrict__ hb,
                                               const int* __restrict__ ro,
                                               const int* __restrict__ ssrc,
                                               unsigned short* __restrict__ aggb, int n) {
    int node = blockIdx.x * 16 + (threadIdx.x >> 4);
    if (node >= n) return;
    int c = (threadIdx.x & 15) * 8;
    int s = ro[node], e = ro[node + 1];
    float acc[8] = {};
    for (int j = s; j < e; ++j) {
        const uint4 v = *(const uint4*)(hb + (size_t)ssrc[j] * D + c);
        acc[0] += b2f_lo(v.x); acc[1] += b2f_hi(v.x);
        acc[2] += b2f_lo(v.y); acc[3] += b2f_hi(v.y);
        acc[4] += b2f_lo(v.z); acc[5] += b2f_hi(v.z);
        acc[6] += b2f_lo(v.w); acc[7] += b2f_hi(v.w);
    }
    ushort4 o0, o1;
    o0.x = f2b(acc[0]); o0.y = f2b(acc[1]); o0.z = f2b(acc[2]); o0.w = f2b(acc[3]);
    o1.x = f2b(acc[4]); o1.y = f2b(acc[5]); o1.z = f2b(acc[6]); o1.w = f2b(acc[7]);
    *(ushort4*)(aggb + (size_t)node * D + c) = o0;
    *(ushort4*)(aggb + (size_t)node * D + c + 4) = o1;
}

// ---------------- fused layer: [agg|h] @ [Wn;Wr] via MFMA ----------------
// 1 wave = 16 rows x 128 cols. K=256 in 8 steps. A from global, B pre-packed.
template<bool LAST>
__global__ __launch_bounds__(256) void k_layer_mfma(
        const unsigned short* __restrict__ hb,
        const unsigned short* __restrict__ aggb,
        const unsigned short* __restrict__ Bp,     // this layer's 64KB pack
        const float* __restrict__ bias,
        const float* __restrict__ x0,
        unsigned short* __restrict__ hb_out,
        const float* __restrict__ fcW,
        const float* __restrict__ fcb,
        float* __restrict__ out, int n) {
    __shared__ unsigned short tsh[4][16][132];     // per-wave transpose buffer
    int wid = threadIdx.x >> 6;
    int lane = threadIdx.x & 63;
    int row0 = (blockIdx.x * 4 + wid) * 16;
    if (row0 >= n) return;

    int r = lane & 15;      // A row / C col-within-frag
    int g = lane >> 4;      // k subgroup / C row group
    const unsigned short* arow = aggb + (size_t)(row0 + r) * D;
    const unsigned short* hrow = hb   + (size_t)(row0 + r) * D;
    const bf16x8* bp = (const bf16x8*)Bp;

    f32x4 acc[8];
    #pragma unroll
    for (int i = 0; i < 8; ++i) { acc[i][0] = 0.f; acc[i][1] = 0.f; acc[i][2] = 0.f; acc[i][3] = 0.f; }

    for (int ks = 0; ks < 8; ++ks) {
        const unsigned short* asrc = (ks < 4) ? (arow + ks * 32 + g * 8)
                                              : (hrow + (ks - 4) * 32 + g * 8);
        bf16x8 afrag = *(const bf16x8*)asrc;
        #pragma unroll
        for (int nb = 0; nb < 8; ++nb) {
            bf16x8 bfrag = bp[(ks * 8 + nb) * 64 + lane];
            acc[nb] = __builtin_amdgcn_mfma_f32_16x16x32_bf16(afrag, bfrag, acc[nb], 0, 0, 0);
        }
    }

    // C layout: row = row0 + g*4 + reg, col = nb*16 + r
    if (!LAST) {
        #pragma unroll
        for (int nb = 0; nb < 8; ++nb) {
            int col = nb * 16 + r;
            float bc = bias[col];
            #pragma unroll
            for (int reg = 0; reg < 4; ++reg) {
                int rowc = row0 + g * 4 + reg;
                float xv = x0[(size_t)rowc * D + col];
                float hv = fmaxf(acc[nb][reg] + bc, 0.f) + xv;
                tsh[wid][g * 4 + reg][col] = f2b(hv);
            }
        }
        // no barrier needed: per-wave buffer
        #pragma unroll
        for (int it = 0; it < 4; ++it) {
            int rr = it * 4 + g;
            uint4 v = *(const uint4*)&tsh[wid][rr][r * 8];
            *(uint4*)(hb_out + (size_t)(row0 + rr) * D + r * 8) = v;
        }
    } else {
        float p[4] = {0.f, 0.f, 0.f, 0.f};
        #pragma unroll
        for (int nb = 0; nb < 8; ++nb) {
            int col = nb * 16 + r;
            float bc = bias[col];
            float fw = fcW[col];
            #pragma unroll
            for (int reg = 0; reg < 4; ++reg) {
                int rowc = row0 + g * 4 + reg;
                float xv = x0[(size_t)rowc * D + col];
                p[reg] += (fmaxf(acc[nb][reg] + bc, 0.f) + xv) * fw;
            }
        }
        #pragma unroll
        for (int reg = 0; reg < 4; ++reg) {
            #pragma unroll
            for (int m = 1; m < 16; m <<= 1) p[reg] += __shfl_xor(p[reg], m, 64);
        }
        if (r == 0) {
            float fb = fcb[0];
            #pragma unroll
            for (int reg = 0; reg < 4; ++reg) out[row0 + g * 4 + reg] = p[reg] + fb;
        }
    }
}

extern "C" void kernel_launch(void* const* d_in, const int* in_sizes, int n_in,
                              void* d_out, int out_size, void* d_ws, size_t ws_size,
                              hipStream_t stream) {
    const float* x    = (const float*)d_in[0];
    const int*   ei   = (const int*)d_in[1];
    const float* Wn   = (const float*)d_in[2];
    const float* Wr   = (const float*)d_in[3];
    const float* bias = (const float*)d_in[4];
    const float* fcW  = (const float*)d_in[5];
    const float* fcb  = (const float*)d_in[6];
    float* out = (float*)d_out;

    const int n = in_sizes[0] / D;     // 50000
    const int e = in_sizes[1] / 2;     // 600000

    const int* src = ei;
    const int* dst = ei + e;

    // workspace
    char* ws = (char*)d_ws;
    unsigned short* xb   = (unsigned short*)ws;  ws += (size_t)n * D * 2;
    unsigned short* hb_a = (unsigned short*)ws;  ws += (size_t)n * D * 2;
    unsigned short* hb_b = (unsigned short*)ws;  ws += (size_t)n * D * 2;
    unsigned short* aggb = (unsigned short*)ws;  ws += (size_t)n * D * 2;
    unsigned short* Bp   = (unsigned short*)ws;  ws += (size_t)4 * 8 * 8 * 64 * 8 * 2;
    int* ro   = (int*)ws;  ws += (size_t)(n + 1) * 4;
    int* cur  = (int*)ws;  ws += (size_t)n * 4;
    int* ssrc = (int*)ws;  ws += (size_t)e * 4;
    int* bsum = (int*)ws;  ws += 256 * 4;
    (void)ws_size;

    const int nscan = (n + 1023) / 1024;

    // CSR build
    k_zero_i32<<<(n + 255) / 256, 256, 0, stream>>>(cur, n);
    k_hist<<<(e + 255) / 256, 256, 0, stream>>>(dst, cur, e);
    k_scan_a<<<nscan, 256, 0, stream>>>(cur, ro, bsum, n);
    k_scan_b<<<1, 64, 0, stream>>>(bsum, ro, nscan, n);
    k_scan_c<<<nscan, 256, 0, stream>>>(ro, cur, bsum, n);
    k_scatter<<<(e + 255) / 256, 256, 0, stream>>>(src, dst, cur, ssrc, e);

    // prep
    int n8 = n * D / 8;
    k_cvt<<<(n8 + 255) / 256, 256, 0, stream>>>(x, xb, n8);
    k_pack_B<<<(4 * 8 * 8 * 64) / 256, 256, 0, stream>>>(Wn, Wr, Bp);

    const int agg_blocks = (n + 15) / 16;
    const int layer_blocks = ((n + 15) / 16 + 3) / 4;
    const size_t bpl = (size_t)8 * 8 * 64 * 8;   // ushorts per layer pack

    // layer 0
    k_agg_b<<<agg_blocks, 256, 0, stream>>>(xb, ro, ssrc, aggb, n);
    k_layer_mfma<false><<<layer_blocks, 256, 0, stream>>>(xb, aggb, Bp,
            bias, x, hb_a, fcW, fcb, out, n);
    // layer 1
    k_agg_b<<<agg_blocks, 256, 0, stream>>>(hb_a, ro, ssrc, aggb, n);
    k_layer_mfma<false><<<layer_blocks, 256, 0, stream>>>(hb_a, aggb, Bp + bpl,
            bias + D, x, hb_b, fcW, fcb, out, n);
    // layer 2
    k_agg_b<<<agg_blocks, 256, 0, stream>>>(hb_b, ro, ssrc, aggb, n);
    k_layer_mfma<false><<<layer_blocks, 256, 0, stream>>>(hb_b, aggb, Bp + 2 * bpl,
            bias + 2 * D, x, hb_a, fcW, fcb, out, n);
    // layer 3 + fused fc
    k_agg_b<<<agg_blocks, 256, 0, stream>>>(hb_a, ro, ssrc, aggb, n);
    k_layer_mfma<true><<<layer_blocks, 256, 0, stream>>>(hb_a, aggb, Bp + 3 * bpl,
            bias + 3 * D, x, hb_b, fcW, fcb, out, n);
}

// Round 5
// 249.604 us; speedup vs baseline: 2.0212x; 1.0963x over previous
//
#include <hip/hip_runtime.h>

// AFGCN: N=50000, E=600000, D=128, L=4. bf16 storage + MFMA, f32 accumulate.
// Fused per layer: gather-aggregate (CSR) directly into A-fragments + GEMM.

#define D 128

using bf16x8 = __attribute__((ext_vector_type(8))) short;
using f32x4  = __attribute__((ext_vector_type(4))) float;

__device__ inline unsigned short f2b(float f) {
    union { float f; unsigned int u; } v; v.f = f;
    unsigned int u = v.u;
    u += 0x7fffu + ((u >> 16) & 1u);   // round-to-nearest-even
    return (unsigned short)(u >> 16);
}
__device__ inline float b2f_lo(unsigned int u) { return __uint_as_float(u << 16); }
__device__ inline float b2f_hi(unsigned int u) { return __uint_as_float(u & 0xffff0000u); }

// ---------------- CSR build ----------------
__global__ void k_zero_i32(int* __restrict__ p, int n) {
    int i = blockIdx.x * blockDim.x + threadIdx.x;
    if (i < n) p[i] = 0;
}

__global__ void k_hist(const int* __restrict__ dst, int* __restrict__ cnt, int e) {
    int i = blockIdx.x * blockDim.x + threadIdx.x;
    if (i < e) atomicAdd(&cnt[dst[i]], 1);
}

__global__ __launch_bounds__(256) void k_scan_a(const int* __restrict__ cnt,
                                                int* __restrict__ ro,
                                                int* __restrict__ bsum, int n) {
    __shared__ int s[256];
    int tid = threadIdx.x;
    int base = blockIdx.x * 1024 + tid * 4;
    int c[4];
    #pragma unroll
    for (int k = 0; k < 4; ++k) c[k] = (base + k < n) ? cnt[base + k] : 0;
    s[tid] = c[0] + c[1] + c[2] + c[3];
    __syncthreads();
    #pragma unroll
    for (int off = 1; off < 256; off <<= 1) {
        int add = (tid >= off) ? s[tid - off] : 0;
        __syncthreads();
        s[tid] += add;
        __syncthreads();
    }
    int run = (tid == 0) ? 0 : s[tid - 1];
    #pragma unroll
    for (int k = 0; k < 4; ++k) {
        if (base + k < n) ro[base + k] = run;
        run += c[k];
    }
    if (tid == 255) bsum[blockIdx.x] = s[255];
}

__global__ __launch_bounds__(64) void k_scan_b(int* __restrict__ bsum,
                                               int* __restrict__ ro, int nb, int n) {
    int tid = threadIdx.x;
    int orig = (tid < nb) ? bsum[tid] : 0;
    int v = orig;
    #pragma unroll
    for (int off = 1; off < 64; off <<= 1) {
        int u = __shfl_up(v, off, 64);
        if (tid >= off) v += u;
    }
    if (tid < nb) bsum[tid] = v - orig;
    if (tid == 63) ro[n] = v;
}

__global__ __launch_bounds__(256) void k_scan_c(int* __restrict__ ro,
                                                int* __restrict__ cur,
                                                const int* __restrict__ bsum, int n) {
    int base = blockIdx.x * 1024 + threadIdx.x * 4;
    int off = bsum[blockIdx.x];
    #pragma unroll
    for (int k = 0; k < 4; ++k) {
        int i = base + k;
        if (i < n) { int v = ro[i] + off; ro[i] = v; cur[i] = v; }
    }
}

__global__ void k_scatter(const int* __restrict__ src, const int* __restrict__ dst,
                          int* __restrict__ cur, int* __restrict__ ssrc, int e) {
    int i = blockIdx.x * blockDim.x + threadIdx.x;
    if (i < e) {
        int pos = atomicAdd(&cur[dst[i]], 1);
        ssrc[pos] = src[i];
    }
}

// ---------------- prep ----------------
__global__ void k_cvt(const float* __restrict__ in, unsigned short* __restrict__ out,
                      int n8) {
    int i = blockIdx.x * blockDim.x + threadIdx.x;
    if (i >= n8) return;
    float4 a = ((const float4*)in)[i * 2];
    float4 b = ((const float4*)in)[i * 2 + 1];
    ushort4 o0, o1;
    o0.x = f2b(a.x); o0.y = f2b(a.y); o0.z = f2b(a.z); o0.w = f2b(a.w);
    o1.x = f2b(b.x); o1.y = f2b(b.y); o1.z = f2b(b.z); o1.w = f2b(b.w);
    ((ushort4*)out)[i * 2] = o0;
    ((ushort4*)out)[i * 2 + 1] = o1;
}

// Pack Bcat = [Wn;Wr] (256x128) into MFMA fragment order, bf16:
// Bp[layer][ks(8)][nb(8)][lane(64)][8]; n = nb*16+(lane&15), k = ks*32+(lane>>4)*8+j
__global__ void k_pack_B(const float* __restrict__ Wn, const float* __restrict__ Wr,
                         unsigned short* __restrict__ Bp) {
    int t = blockIdx.x * blockDim.x + threadIdx.x;   // < 4*8*8*64
    int lane = t & 63;
    int nb = (t >> 6) & 7;
    int ks = (t >> 9) & 7;
    int l  = t >> 12;
    int ncol = nb * 16 + (lane & 15);
    int k0 = ks * 32 + (lane >> 4) * 8;
    ushort4 lo, hi;
    unsigned short v[8];
    #pragma unroll
    for (int j = 0; j < 8; ++j) {
        int k = k0 + j;
        float f = (k < D) ? Wn[(size_t)l * D * D + k * D + ncol]
                          : Wr[(size_t)l * D * D + (k - D) * D + ncol];
        v[j] = f2b(f);
    }
    lo.x = v[0]; lo.y = v[1]; lo.z = v[2]; lo.w = v[3];
    hi.x = v[4]; hi.y = v[5]; hi.z = v[6]; hi.w = v[7];
    ((ushort4*)Bp)[t * 2] = lo;
    ((ushort4*)Bp)[t * 2 + 1] = hi;
}

// ---------------- fused layer: CSR-gather-agg + [agg|h] @ [Wn;Wr] MFMA ----------------
// 1 wave = 16 rows x 128 cols. Lane (r=lane&15, g=lane>>4) accumulates its own
// A-fragment strips agg[ks][8] (cols ks*32+g*8..+7 of row row0+r) during the gather.
template<bool LAST>
__global__ __launch_bounds__(256) void k_fused(
        const unsigned short* __restrict__ hb,
        const int* __restrict__ ro,
        const int* __restrict__ ssrc,
        const unsigned short* __restrict__ Bp,     // this layer's 64KB pack
        const float* __restrict__ bias,
        const float* __restrict__ x0,
        unsigned short* __restrict__ hb_out,
        const float* __restrict__ fcW,
        const float* __restrict__ fcb,
        float* __restrict__ out, int n) {
    __shared__ unsigned short tsh[4][16][132];     // per-wave transpose buffer
    int wid = threadIdx.x >> 6;
    int lane = threadIdx.x & 63;
    int row0 = (blockIdx.x * 4 + wid) * 16;
    if (row0 >= n) return;

    int r = lane & 15;      // A row / C col-within-frag
    int g = lane >> 4;      // k subgroup / C row group
    int row = row0 + r;

    // ---- gather-aggregate into per-lane A strips (f32) ----
    float agg[4][8];
    #pragma unroll
    for (int ks = 0; ks < 4; ++ks)
        #pragma unroll
        for (int t = 0; t < 8; ++t) agg[ks][t] = 0.f;

    int s = ro[row], e = ro[row + 1];
    const unsigned short* hbg = hb + g * 8;
    for (int j = s; j < e; ++j) {
        const unsigned short* srcp = hbg + (size_t)ssrc[j] * D;
        uint4 v0 = *(const uint4*)(srcp);
        uint4 v1 = *(const uint4*)(srcp + 32);
        uint4 v2 = *(const uint4*)(srcp + 64);
        uint4 v3 = *(const uint4*)(srcp + 96);
        agg[0][0] += b2f_lo(v0.x); agg[0][1] += b2f_hi(v0.x);
        agg[0][2] += b2f_lo(v0.y); agg[0][3] += b2f_hi(v0.y);
        agg[0][4] += b2f_lo(v0.z); agg[0][5] += b2f_hi(v0.z);
        agg[0][6] += b2f_lo(v0.w); agg[0][7] += b2f_hi(v0.w);
        agg[1][0] += b2f_lo(v1.x); agg[1][1] += b2f_hi(v1.x);
        agg[1][2] += b2f_lo(v1.y); agg[1][3] += b2f_hi(v1.y);
        agg[1][4] += b2f_lo(v1.z); agg[1][5] += b2f_hi(v1.z);
        agg[1][6] += b2f_lo(v1.w); agg[1][7] += b2f_hi(v1.w);
        agg[2][0] += b2f_lo(v2.x); agg[2][1] += b2f_hi(v2.x);
        agg[2][2] += b2f_lo(v2.y); agg[2][3] += b2f_hi(v2.y);
        agg[2][4] += b2f_lo(v2.z); agg[2][5] += b2f_hi(v2.z);
        agg[2][6] += b2f_lo(v2.w); agg[2][7] += b2f_hi(v2.w);
        agg[3][0] += b2f_lo(v3.x); agg[3][1] += b2f_hi(v3.x);
        agg[3][2] += b2f_lo(v3.y); agg[3][3] += b2f_hi(v3.y);
        agg[3][4] += b2f_lo(v3.z); agg[3][5] += b2f_hi(v3.z);
        agg[3][6] += b2f_lo(v3.w); agg[3][7] += b2f_hi(v3.w);
    }

    // ---- GEMM: K=256 (4 agg steps from registers, 4 h steps from global) ----
    f32x4 acc[8];
    #pragma unroll
    for (int i = 0; i < 8; ++i) {
        acc[i][0] = 0.f; acc[i][1] = 0.f; acc[i][2] = 0.f; acc[i][3] = 0.f;
    }
    const bf16x8* bp = (const bf16x8*)Bp;

    #pragma unroll
    for (int ks = 0; ks < 4; ++ks) {
        unsigned short af[8];
        #pragma unroll
        for (int t = 0; t < 8; ++t) af[t] = f2b(agg[ks][t]);
        bf16x8 afrag = *(const bf16x8*)af;
        #pragma unroll
        for (int nb = 0; nb < 8; ++nb) {
            bf16x8 bfrag = bp[(ks * 8 + nb) * 64 + lane];
            acc[nb] = __builtin_amdgcn_mfma_f32_16x16x32_bf16(afrag, bfrag, acc[nb], 0, 0, 0);
        }
    }
    const unsigned short* hrow = hb + (size_t)row * D;
    #pragma unroll
    for (int ks = 4; ks < 8; ++ks) {
        bf16x8 afrag = *(const bf16x8*)(hrow + (ks - 4) * 32 + g * 8);
        #pragma unroll
        for (int nb = 0; nb < 8; ++nb) {
            bf16x8 bfrag = bp[(ks * 8 + nb) * 64 + lane];
            acc[nb] = __builtin_amdgcn_mfma_f32_16x16x32_bf16(afrag, bfrag, acc[nb], 0, 0, 0);
        }
    }

    // C layout: row = row0 + g*4 + reg, col = nb*16 + r
    if (!LAST) {
        #pragma unroll
        for (int nb = 0; nb < 8; ++nb) {
            int col = nb * 16 + r;
            float bc = bias[col];
            #pragma unroll
            for (int reg = 0; reg < 4; ++reg) {
                int rowc = row0 + g * 4 + reg;
                float xv = x0[(size_t)rowc * D + col];
                float hv = fmaxf(acc[nb][reg] + bc, 0.f) + xv;
                tsh[wid][g * 4 + reg][col] = f2b(hv);
            }
        }
        // per-wave buffer: wave-internal LDS dependency, no barrier needed
        #pragma unroll
        for (int it = 0; it < 4; ++it) {
            int rr = it * 4 + g;
            uint4 v = *(const uint4*)&tsh[wid][rr][r * 8];
            *(uint4*)(hb_out + (size_t)(row0 + rr) * D + r * 8) = v;
        }
    } else {
        float p[4] = {0.f, 0.f, 0.f, 0.f};
        #pragma unroll
        for (int nb = 0; nb < 8; ++nb) {
            int col = nb * 16 + r;
            float bc = bias[col];
            float fw = fcW[col];
            #pragma unroll
            for (int reg = 0; reg < 4; ++reg) {
                int rowc = row0 + g * 4 + reg;
                float xv = x0[(size_t)rowc * D + col];
                p[reg] += (fmaxf(acc[nb][reg] + bc, 0.f) + xv) * fw;
            }
        }
        #pragma unroll
        for (int reg = 0; reg < 4; ++reg) {
            #pragma unroll
            for (int m = 1; m < 16; m <<= 1) p[reg] += __shfl_xor(p[reg], m, 64);
        }
        if (r == 0) {
            float fb = fcb[0];
            #pragma unroll
            for (int reg = 0; reg < 4; ++reg) out[row0 + g * 4 + reg] = p[reg] + fb;
        }
    }
}

extern "C" void kernel_launch(void* const* d_in, const int* in_sizes, int n_in,
                              void* d_out, int out_size, void* d_ws, size_t ws_size,
                              hipStream_t stream) {
    const float* x    = (const float*)d_in[0];
    const int*   ei   = (const int*)d_in[1];
    const float* Wn   = (const float*)d_in[2];
    const float* Wr   = (const float*)d_in[3];
    const float* bias = (const float*)d_in[4];
    const float* fcW  = (const float*)d_in[5];
    const float* fcb  = (const float*)d_in[6];
    float* out = (float*)d_out;

    const int n = in_sizes[0] / D;     // 50000
    const int e = in_sizes[1] / 2;     // 600000

    const int* src = ei;
    const int* dst = ei + e;

    // workspace
    char* ws = (char*)d_ws;
    unsigned short* xb   = (unsigned short*)ws;  ws += (size_t)n * D * 2;
    unsigned short* hb_a = (unsigned short*)ws;  ws += (size_t)n * D * 2;
    unsigned short* hb_b = (unsigned short*)ws;  ws += (size_t)n * D * 2;
    unsigned short* Bp   = (unsigned short*)ws;  ws += (size_t)4 * 8 * 8 * 64 * 8 * 2;
    int* ro   = (int*)ws;  ws += (size_t)(n + 1) * 4;
    int* cur  = (int*)ws;  ws += (size_t)n * 4;
    int* ssrc = (int*)ws;  ws += (size_t)e * 4;
    int* bsum = (int*)ws;  ws += 256 * 4;
    (void)ws_size;

    const int nscan = (n + 1023) / 1024;

    // CSR build
    k_zero_i32<<<(n + 255) / 256, 256, 0, stream>>>(cur, n);
    k_hist<<<(e + 255) / 256, 256, 0, stream>>>(dst, cur, e);
    k_scan_a<<<nscan, 256, 0, stream>>>(cur, ro, bsum, n);
    k_scan_b<<<1, 64, 0, stream>>>(bsum, ro, nscan, n);
    k_scan_c<<<nscan, 256, 0, stream>>>(ro, cur, bsum, n);
    k_scatter<<<(e + 255) / 256, 256, 0, stream>>>(src, dst, cur, ssrc, e);

    // prep
    int n8 = n * D / 8;
    k_cvt<<<(n8 + 255) / 256, 256, 0, stream>>>(x, xb, n8);
    k_pack_B<<<(4 * 8 * 8 * 64) / 256, 256, 0, stream>>>(Wn, Wr, Bp);

    const int layer_blocks = ((n + 15) / 16 + 3) / 4;
    const size_t bpl = (size_t)8 * 8 * 64 * 8;   // ushorts per layer pack

    k_fused<false><<<layer_blocks, 256, 0, stream>>>(xb, ro, ssrc, Bp,
            bias, x, hb_a, fcW, fcb, out, n);
    k_fused<false><<<layer_blocks, 256, 0, stream>>>(hb_a, ro, ssrc, Bp + bpl,
            bias + D, x, hb_b, fcW, fcb, out, n);
    k_fused<false><<<layer_blocks, 256, 0, stream>>>(hb_b, ro, ssrc, Bp + 2 * bpl,
            bias + 2 * D, x, hb_a, fcW, fcb, out, n);
    k_fused<true><<<layer_blocks, 256, 0, stream>>>(hb_a, ro, ssrc, Bp + 3 * bpl,
            bias + 3 * D, x, hb_b, fcW, fcb, out, n);
}